// Round 6
// baseline (394.432 us; speedup 1.0000x reference)
//
#include <hip/hip_runtime.h>
#include <hip/hip_bf16.h>
#include <math.h>

#define D_MODEL 768
#define N_HEADS 12
#define HD 64
#define SEQ 2048
#define BATCH 4
#define M_ROWS 8192
#define D_FF 3072
#define QKV_DIM 2304
#define LN_EPS 1e-5f
// 0.125 * log2(e): folded into Q so P = exp2(S') directly
#define Q_SCALE 0.18033688011112042f

typedef __attribute__((ext_vector_type(8))) short bf16x8;
typedef __attribute__((ext_vector_type(4))) float f32x4;
typedef __hip_bfloat16 bf16;

__device__ __forceinline__ void store_val(float* p, float v) { *p = v; }
__device__ __forceinline__ void store_val(bf16* p, float v) { *p = __float2bfloat16(v); }

// fast bf16 pair pack: round-half-up (add 0x8000) + v_perm high-half extract
__device__ __forceinline__ unsigned int pack_bf16_pair(float a, float b) {
    unsigned int ua = __builtin_bit_cast(unsigned int, a) + 0x8000u;
    unsigned int ub = __builtin_bit_cast(unsigned int, b) + 0x8000u;
    // D = {ub.hi16, ua.hi16}: sel bytes {7,6,3,2} of (s0=ub, s1=ua)
    return __builtin_amdgcn_perm(ub, ua, 0x07060302u);
}

__device__ __forceinline__ void async_load16(const void* g, void* l) {
    __builtin_amdgcn_global_load_lds(
        (const __attribute__((address_space(1))) void*)g,
        (__attribute__((address_space(3))) void*)l, 16, 0, 0);
}

// ---------------- LN1 (bf16 out) + fused weight casts -----------------
__global__ __launch_bounds__(256) void ln1_cast(
        const float* __restrict__ x, const float* __restrict__ w,
        const float* __restrict__ b, bf16* __restrict__ y,
        const float* __restrict__ s0, bf16* __restrict__ d0, int n0,
        const float* __restrict__ s1, bf16* __restrict__ d1, int n1,
        const float* __restrict__ s2, bf16* __restrict__ d2, int n2,
        const float* __restrict__ s3, bf16* __restrict__ d3, int n3) {
    int t = threadIdx.x;
    if (blockIdx.x >= M_ROWS) {
        int i = (blockIdx.x - M_ROWS) * 256 + t;   // float4 index
        const float* s; bf16* d; int local = i;
        if (local < n0) { s = s0; d = d0; }
        else {
            local -= n0;
            if (local < n1) { s = s1; d = d1; }
            else {
                local -= n1;
                if (local < n2) { s = s2; d = d2; }
                else {
                    local -= n2;
                    if (local >= n3) return;
                    s = s3; d = d3;
                }
            }
        }
        float4 v = ((const float4*)s)[local];
        uint2 pk;
        pk.x = pack_bf16_pair(v.x, v.y);
        pk.y = pack_bf16_pair(v.z, v.w);
        *(uint2*)(d + local * 4) = pk;
        return;
    }
    int row = blockIdx.x;
    const float* xr = x + (size_t)row * D_MODEL;
    bf16* yr = y + (size_t)row * D_MODEL;
    float v0 = xr[t], v1 = xr[t + 256], v2 = xr[t + 512];
    float s  = v0 + v1 + v2;
    float sq = v0 * v0 + v1 * v1 + v2 * v2;
    #pragma unroll
    for (int off = 32; off; off >>= 1) {
        s  += __shfl_xor(s, off);
        sq += __shfl_xor(sq, off);
    }
    __shared__ float ss[4], ssq[4];
    int wave = t >> 6;
    if ((t & 63) == 0) { ss[wave] = s; ssq[wave] = sq; }
    __syncthreads();
    s  = ss[0] + ss[1] + ss[2] + ss[3];
    sq = ssq[0] + ssq[1] + ssq[2] + ssq[3];
    float mean = s * (1.0f / D_MODEL);
    float var  = sq * (1.0f / D_MODEL) - mean * mean;
    float rstd = rsqrtf(var + LN_EPS);
    yr[t]       = __float2bfloat16((v0 - mean) * rstd * w[t]       + b[t]);
    yr[t + 256] = __float2bfloat16((v1 - mean) * rstd * w[t + 256] + b[t + 256]);
    yr[t + 512] = __float2bfloat16((v2 - mean) * rstd * w[t + 512] + b[t + 512]);
}

// ---------------- LayerNorm (LN2) ----------------
template <typename OutT>
__global__ __launch_bounds__(256) void ln_kernel(const float* __restrict__ x,
                                                 const float* __restrict__ w,
                                                 const float* __restrict__ b,
                                                 OutT* __restrict__ y) {
    int row = blockIdx.x;
    const float* xr = x + (size_t)row * D_MODEL;
    OutT* yr = y + (size_t)row * D_MODEL;
    int t = threadIdx.x;
    float v0 = xr[t], v1 = xr[t + 256], v2 = xr[t + 512];
    float s  = v0 + v1 + v2;
    float sq = v0 * v0 + v1 * v1 + v2 * v2;
    #pragma unroll
    for (int off = 32; off; off >>= 1) {
        s  += __shfl_xor(s, off);
        sq += __shfl_xor(sq, off);
    }
    __shared__ float ss[4], ssq[4];
    int wave = t >> 6;
    if ((t & 63) == 0) { ss[wave] = s; ssq[wave] = sq; }
    __syncthreads();
    s  = ss[0] + ss[1] + ss[2] + ss[3];
    sq = ssq[0] + ssq[1] + ssq[2] + ssq[3];
    float mean = s * (1.0f / D_MODEL);
    float var  = sq * (1.0f / D_MODEL) - mean * mean;
    float rstd = rsqrtf(var + LN_EPS);
    store_val(yr + t,       (v0 - mean) * rstd * w[t]       + b[t]);
    store_val(yr + t + 256, (v1 - mean) * rstd * w[t + 256] + b[t + 256]);
    store_val(yr + t + 512, (v2 - mean) * rstd * w[t + 512] + b[t + 512]);
}

// tanh-form GELU via hw exp2 + rcp (max abs err ~3e-4 vs erf form)
__device__ __forceinline__ float gelu_fast(float v) {
    float u = v * (0.7978845608f + 0.0356774081f * v * v);
    u = fminf(fmaxf(u, -10.0f), 10.0f);
    float e = __builtin_amdgcn_exp2f(u * 2.8853900818f);   // e = exp(2u)
    float th = (e - 1.0f) * __builtin_amdgcn_rcpf(e + 1.0f);
    return 0.5f * v * (1.0f + th);
}

// ---- bf16 MFMA GEMM 256sq: 8-phase template port (BM=BN=256, BK=64) ----
// 8 waves (2M x 4N), wave tile 128x64 (384 B LDS/MFMA vs 512 at 64x64),
// 2 K-tile LDS buffers (128 KB), 1 block/CU. Per K-tile, 4 phases by
// C-quadrant (mh,nh) = (0,0)->(0,1)->(1,1)->(1,0), each phase loads only
// the operand set that changed (12/4/8/0 ds_reads), then
// {barrier; lgkmcnt(0); setprio(1); 16 MFMA; setprio(0); barrier}.
// Counted vmcnt ONCE per K-tile: stage = 8 loads/thread; at tile top
// in-flight = tile ki (8, oldest) + tile ki+1 (8) -> vmcnt(8) retires ki
// and leaves ki+1 in flight across the barrier (last iter: vmcnt(0)).
// STAGE(ki+2)->buf[cur] is issued in ph3: ph2's post-MFMA barrier proves
// every wave passed its lgkmcnt(0), i.e. all reads of buf[cur] are done.
// FUSE: 1 = bias+gelu, 3 = qkv (cols<768 *= Q_SCALE)
template <int FUSE, typename OutT>
__global__ __launch_bounds__(512, 2) void gemm_256(const bf16* __restrict__ A,
                                                   const bf16* __restrict__ W,
                                                   const float* __restrict__ bias,
                                                   OutT* __restrict__ C,
                                                   int M, int N, int K) {
    __shared__ __align__(16) bf16 As[2][256 * 64];   // 2 x 32 KB
    __shared__ __align__(16) bf16 Bs[2][256 * 64];   // 2 x 32 KB
    int t = threadIdx.x;
    int wave = t >> 6, lane = t & 63;

    // XCD-aware bijective remap (nwg % 8 == 0 for both users: 288, 384)
    int nbx = gridDim.x;
    int w0 = blockIdx.x + nbx * blockIdx.y;
    int cpx = (nbx * gridDim.y) >> 3;
    int wg = (w0 & 7) * cpx + (w0 >> 3);
    int m_base = (wg / nbx) * 256, n_base = (wg % nbx) * 256;

    int wm = (wave >> 2) * 128;       // 2 M-wave-groups
    int wn = (wave & 3) * 64;         // 4 N-wave-groups
    int c = lane & 15, rr = lane >> 4;
    int cx = c & 7;

    f32x4 acc[8][4] = {};             // [mh*4+mi][nh*2+ni]

    // staging: 16B-slot s = r*512 + t; row = s>>3, p = s&7; global chunk
    // kc = p ^ (row&7) (XOR swizzle via source); LDS dest linear,
    // wave-uniform base + lane*16 (global_load_lds requirement)
    const bf16* Ag[4]; const bf16* Bg[4];
    int loff[4];
    #pragma unroll
    for (int r = 0; r < 4; r++) {
        int s = r * 512 + t;
        int row = s >> 3, p = s & 7;
        int kc = p ^ (row & 7);
        Ag[r] = A + (size_t)(m_base + row) * K + kc * 8;
        Bg[r] = W + (size_t)(n_base + row) * K + kc * 8;
        loff[r] = (r * 512 + wave * 64) * 8;
    }

    auto STAGE = [&](int kt, int buf) {
        int k0 = kt * 64;
        #pragma unroll
        for (int r = 0; r < 4; r++) {
            async_load16(Ag[r] + k0, As[buf] + loff[r]);
            async_load16(Bg[r] + k0, Bs[buf] + loff[r]);
        }
    };

    int nk = K / 64;                  // = 12 here (>= 3 required)
    STAGE(0, 0);
    STAGE(1, 1);

    for (int ki = 0; ki < nk; ki++) {
        int cur = ki & 1;
        const bf16* Ab = As[cur];
        const bf16* Bb = Bs[cur];

        if (ki < nk - 1) {
            asm volatile("s_waitcnt vmcnt(8)" ::: "memory");
        } else {
            asm volatile("s_waitcnt vmcnt(0)" ::: "memory");
        }
        __builtin_amdgcn_s_barrier();          // buf[cur] staged (cross-wave)
        __builtin_amdgcn_sched_barrier(0);

        bf16x8 af[4][2];          // A-frags of current mh  [mi][kk]
        bf16x8 bfr[2][2][2];      // B-frags, both nh kept  [nh][ni][kk]

        // ---- ph0: read A(mh0) 8 + B(nh0) 4; MFMA (mh0,nh0)
        #pragma unroll
        for (int mi = 0; mi < 4; mi++)
            #pragma unroll
            for (int kk = 0; kk < 2; kk++)
                af[mi][kk] = *(const bf16x8*)&Ab[(wm + mi * 16 + c) * 64 + (((kk << 2) + rr) ^ cx) * 8];
        #pragma unroll
        for (int ni = 0; ni < 2; ni++)
            #pragma unroll
            for (int kk = 0; kk < 2; kk++)
                bfr[0][ni][kk] = *(const bf16x8*)&Bb[(wn + ni * 16 + c) * 64 + (((kk << 2) + rr) ^ cx) * 8];
        __builtin_amdgcn_s_barrier();
        asm volatile("s_waitcnt lgkmcnt(0)" ::: "memory");
        __builtin_amdgcn_sched_barrier(0);
        __builtin_amdgcn_s_setprio(1);
        #pragma unroll
        for (int kk = 0; kk < 2; kk++)
            #pragma unroll
            for (int mi = 0; mi < 4; mi++)
                #pragma unroll
                for (int ni = 0; ni < 2; ni++)
                    acc[mi][ni] = __builtin_amdgcn_mfma_f32_16x16x32_bf16(
                        bfr[0][ni][kk], af[mi][kk], acc[mi][ni], 0, 0, 0);
        __builtin_amdgcn_s_setprio(0);
        __builtin_amdgcn_s_barrier();

        // ---- ph1: read B(nh1) 4; MFMA (mh0,nh1)
        #pragma unroll
        for (int ni = 0; ni < 2; ni++)
            #pragma unroll
            for (int kk = 0; kk < 2; kk++)
                bfr[1][ni][kk] = *(const bf16x8*)&Bb[(wn + 32 + ni * 16 + c) * 64 + (((kk << 2) + rr) ^ cx) * 8];
        __builtin_amdgcn_s_barrier();
        asm volatile("s_waitcnt lgkmcnt(0)" ::: "memory");
        __builtin_amdgcn_sched_barrier(0);
        __builtin_amdgcn_s_setprio(1);
        #pragma unroll
        for (int kk = 0; kk < 2; kk++)
            #pragma unroll
            for (int mi = 0; mi < 4; mi++)
                #pragma unroll
                for (int ni = 0; ni < 2; ni++)
                    acc[mi][2 + ni] = __builtin_amdgcn_mfma_f32_16x16x32_bf16(
                        bfr[1][ni][kk], af[mi][kk], acc[mi][2 + ni], 0, 0, 0);
        __builtin_amdgcn_s_setprio(0);
        __builtin_amdgcn_s_barrier();

        // ---- ph2: read A(mh1) 8; MFMA (mh1,nh1)
        #pragma unroll
        for (int mi = 0; mi < 4; mi++)
            #pragma unroll
            for (int kk = 0; kk < 2; kk++)
                af[mi][kk] = *(const bf16x8*)&Ab[(wm + 64 + mi * 16 + c) * 64 + (((kk << 2) + rr) ^ cx) * 8];
        __builtin_amdgcn_s_barrier();
        asm volatile("s_waitcnt lgkmcnt(0)" ::: "memory");
        __builtin_amdgcn_sched_barrier(0);
        __builtin_amdgcn_s_setprio(1);
        #pragma unroll
        for (int kk = 0; kk < 2; kk++)
            #pragma unroll
            for (int mi = 0; mi < 4; mi++)
                #pragma unroll
                for (int ni = 0; ni < 2; ni++)
                    acc[4 + mi][2 + ni] = __builtin_amdgcn_mfma_f32_16x16x32_bf16(
                        bfr[1][ni][kk], af[mi][kk], acc[4 + mi][2 + ni], 0, 0, 0);
        __builtin_amdgcn_s_setprio(0);
        __builtin_amdgcn_s_barrier();          // all reads of buf[cur] done

        // ---- ph3: issue STAGE(ki+2) -> buf[cur]; MFMA (mh1,nh0) from regs
        if (ki + 2 < nk) STAGE(ki + 2, cur);
        __builtin_amdgcn_s_setprio(1);
        #pragma unroll
        for (int kk = 0; kk < 2; kk++)
            #pragma unroll
            for (int mi = 0; mi < 4; mi++)
                #pragma unroll
                for (int ni = 0; ni < 2; ni++)
                    acc[4 + mi][ni] = __builtin_amdgcn_mfma_f32_16x16x32_bf16(
                        bfr[0][ni][kk], af[mi][kk], acc[4 + mi][ni], 0, 0, 0);
        __builtin_amdgcn_s_setprio(0);
        __builtin_amdgcn_s_barrier();
    }

    // epilogue: acc[mi][ni][reg] = C[m_base+wm+mi*16+c][n_base+wn+ni*16+rr*4+reg]
    #pragma unroll
    for (int mi = 0; mi < 8; mi++) {
        int m = m_base + wm + mi * 16 + c;
        #pragma unroll
        for (int ni = 0; ni < 4; ni++) {
            int n0 = n_base + wn + ni * 16 + rr * 4;
            float4 bv = *(const float4*)&bias[n0];
            float v0 = acc[mi][ni][0] + bv.x;
            float v1 = acc[mi][ni][1] + bv.y;
            float v2 = acc[mi][ni][2] + bv.z;
            float v3 = acc[mi][ni][3] + bv.w;
            if (FUSE == 1) {
                v0 = gelu_fast(v0); v1 = gelu_fast(v1);
                v2 = gelu_fast(v2); v3 = gelu_fast(v3);
            }
            if (FUSE == 3 && n0 < 768) {
                v0 *= Q_SCALE; v1 *= Q_SCALE; v2 *= Q_SCALE; v3 *= Q_SCALE;
            }
            OutT* dst = C + (size_t)m * N + n0;
            if (sizeof(OutT) == 4) {
                float4 st = {v0, v1, v2, v3};
                *(float4*)dst = st;
            } else {
                uint2 pk;
                pk.x = pack_bf16_pair(v0, v1);
                pk.y = pack_bf16_pair(v2, v3);
                *(uint2*)dst = pk;
            }
        }
    }
}

// ---------------- bf16 MFMA GEMM v4: C = A[M,K] · W[N,K]^T + bias ----------
// BM=BN=128, BK=64, 4 waves (2x2), 2 LDS buffers, counted vmcnt, 2 blocks/CU.
// Kept for the N=768 GEMMs (out/proj) where 256-tiles leave CUs idle.
// FUSE: 0 = bias, 1 = bias+gelu, 2 = bias+resid(fp32), 3 = qkv (cols<768 *= Q_SCALE)
template <int FUSE, typename OutT>
__global__ __launch_bounds__(256) void gemm_mfma(const bf16* __restrict__ A,
                                                 const bf16* __restrict__ W,
                                                 const float* __restrict__ bias,
                                                 const float* __restrict__ resid,
                                                 OutT* __restrict__ C,
                                                 int M, int N, int K) {
    const int BK = 64;
    __shared__ __align__(16) bf16 As[2][128 * BK];   // 2 x 16 KB
    __shared__ __align__(16) bf16 Bs[2][128 * BK];   // 2 x 16 KB
    int t = threadIdx.x;
    int wave = t >> 6, lane = t & 63;

    // XCD-aware bijective remap of the flat block id
    int nbx = gridDim.x;
    int w0 = blockIdx.x + nbx * blockIdx.y;
    int cpx = (nbx * gridDim.y) >> 3;            // nwg / 8 (nwg % 8 == 0)
    int wg = (w0 & 7) * cpx + (w0 >> 3);
    int m_base = (wg / nbx) * 128, n_base = (wg % nbx) * 128;

    int wm = (wave >> 1) * 64, wn = (wave & 1) * 64;
    int c = lane & 15, rr = lane >> 4;
    int cx = c & 7;

    f32x4 acc[4][4] = {};

    const bf16* Ag[4]; const bf16* Bg[4];
    int loff[4];
    #pragma unroll
    for (int r = 0; r < 4; r++) {
        int s = r * 256 + t;
        int row = s >> 3, p = s & 7;
        int kc = p ^ (row & 7);
        Ag[r] = A + (size_t)(m_base + row) * K + kc * 8;
        Bg[r] = W + (size_t)(n_base + row) * K + kc * 8;
        loff[r] = (r * 256 + wave * 64) * 8;
    }

    auto STAGE = [&](int kt, int buf) {
        int k0 = kt * BK;
        #pragma unroll
        for (int r = 0; r < 4; r++) {
            async_load16(Ag[r] + k0, As[buf] + loff[r]);
            async_load16(Bg[r] + k0, Bs[buf] + loff[r]);
        }
    };

    int nk = K / BK;
    STAGE(0, 0);
    STAGE(1, 1);

    for (int ki = 0; ki < nk; ki++) {
        int cur = ki & 1;
        if (ki < nk - 1) {
            asm volatile("s_waitcnt vmcnt(8)" ::: "memory");
        } else {
            asm volatile("s_waitcnt vmcnt(0)" ::: "memory");
        }
        __builtin_amdgcn_s_barrier();            // b1: buf[cur] ready
        __builtin_amdgcn_sched_barrier(0);

        // register-stage all fragments of tile ki (frees buf[cur])
        bf16x8 af[2][4], bfr[2][4];
        #pragma unroll
        for (int kk = 0; kk < 2; kk++) {
            int sw = ((kk * 4 + rr) ^ cx) * 8;
            #pragma unroll
            for (int mi = 0; mi < 4; mi++)
                af[kk][mi] = *(const bf16x8*)&As[cur][(wm + mi * 16 + c) * BK + sw];
            #pragma unroll
            for (int ni = 0; ni < 4; ni++)
                bfr[kk][ni] = *(const bf16x8*)&Bs[cur][(wn + ni * 16 + c) * BK + sw];
        }
        asm volatile("s_waitcnt lgkmcnt(0)" ::: "memory");
        __builtin_amdgcn_s_barrier();            // b2: all waves read buf[cur]
        __builtin_amdgcn_sched_barrier(0);

        if (ki + 2 < nk) STAGE(ki + 2, cur);     // overwrite buf[cur]

        __builtin_amdgcn_s_setprio(1);
        #pragma unroll
        for (int kk = 0; kk < 2; kk++)
            #pragma unroll
            for (int mi = 0; mi < 4; mi++)
                #pragma unroll
                for (int ni = 0; ni < 4; ni++)
                    acc[mi][ni] = __builtin_amdgcn_mfma_f32_16x16x32_bf16(
                        bfr[kk][ni], af[kk][mi], acc[mi][ni], 0, 0, 0);
        __builtin_amdgcn_s_setprio(0);
    }

    #pragma unroll
    for (int mi = 0; mi < 4; mi++) {
        int m = m_base + wm + mi * 16 + c;
        #pragma unroll
        for (int ni = 0; ni < 4; ni++) {
            int n0 = n_base + wn + ni * 16 + rr * 4;
            float4 bv = *(const float4*)&bias[n0];
            float v0 = acc[mi][ni][0] + bv.x;
            float v1 = acc[mi][ni][1] + bv.y;
            float v2 = acc[mi][ni][2] + bv.z;
            float v3 = acc[mi][ni][3] + bv.w;
            if (FUSE == 1) {
                v0 = gelu_fast(v0); v1 = gelu_fast(v1);
                v2 = gelu_fast(v2); v3 = gelu_fast(v3);
            }
            if (FUSE == 2) {
                float4 rv = *(const float4*)&resid[(size_t)m * N + n0];
                v0 += rv.x; v1 += rv.y; v2 += rv.z; v3 += rv.w;
            }
            if (FUSE == 3 && n0 < 768) {
                v0 *= Q_SCALE; v1 *= Q_SCALE; v2 *= Q_SCALE; v3 *= Q_SCALE;
            }
            OutT* dst = C + (size_t)m * N + n0;
            if (sizeof(OutT) == 4) {
                float4 st = {v0, v1, v2, v3};
                *(float4*)dst = st;
            } else {
                uint2 pk;
                pk.x = pack_bf16_pair(v0, v1);
                pk.y = pack_bf16_pair(v2, v3);
                *(uint2*)dst = pk;
            }
        }
    }
}

// ---------------- V transpose: qkvb V-part [s][d] -> vt[(b,h,d)][s] --------
__global__ __launch_bounds__(256) void vtrans(const bf16* __restrict__ qkvb,
                                              bf16* __restrict__ vt) {
    __shared__ bf16 T[64 * 72];
    int t = threadIdx.x;
    int s0 = blockIdx.x * 64, h = blockIdx.y, b = blockIdx.z;
    const bf16* src = qkvb + (size_t)(b * SEQ) * QKV_DIM + 2 * D_MODEL + h * HD;
    #pragma unroll
    for (int i = 0; i < 2; i++) {
        int idx = i * 256 + t;
        int sr = idx >> 3, ch = idx & 7;
        uint4 v = *(const uint4*)(src + (size_t)(s0 + sr) * QKV_DIM + ch * 8);
        *(uint4*)&T[sr * 72 + ch * 8] = v;
    }
    __syncthreads();
    int dr = t >> 2, part = t & 3;
    unsigned int w[8];
    #pragma unroll
    for (int i = 0; i < 8; i++) {
        unsigned short a, bsh;
        __builtin_memcpy(&a,   &T[(part * 16 + 2 * i    ) * 72 + dr], 2);
        __builtin_memcpy(&bsh, &T[(part * 16 + 2 * i + 1) * 72 + dr], 2);
        w[i] = (unsigned int)a | ((unsigned int)bsh << 16);
    }
    bf16* dst = vt + ((size_t)((b * N_HEADS + h) * HD + dr)) * SEQ + s0 + part * 16;
    uint4 p0; p0.x = w[0]; p0.y = w[1]; p0.z = w[2]; p0.w = w[3];
    uint4 p1; p1.x = w[4]; p1.y = w[5]; p1.z = w[6]; p1.w = w[7];
    *(uint4*)dst = p0;
    *(uint4*)(dst + 8) = p1;
}

// ---------------- MFMA flash attention ----------------
// Unchanged from round 5 (XCD swizzle cut HBM fetch 5.7x; kernel is
// softmax-VALU-bound at ~73 us -- structural plateau for this shape).
__global__ __launch_bounds__(256) void attn_mfma(const bf16* __restrict__ qkvb,
                                                 const bf16* __restrict__ vt,
                                                 bf16* __restrict__ o) {
    __shared__ __align__(16) bf16 Ks[2 * 64 * 64];    // 16 KB (dbuf)
    __shared__ __align__(16) bf16 Vts[2 * 64 * 64];   // 16 KB (dbuf)
    __shared__ __align__(16) bf16 Ps[128 * 64];       // 16 KB (also Q staging)

    int t = threadIdx.x;
    int wave = t >> 6, lane = t & 63;

    // XCD swizzle (bijective on 768): wg = (w%8)*96 + w/8
    int w0 = blockIdx.x + 16 * (blockIdx.y + 12 * blockIdx.z);
    int wg = (w0 & 7) * 96 + (w0 >> 3);
    int qt = wg & 15;
    int hb = wg >> 4;                 // 0..47
    int h = hb % 12, b = hb / 12;

    int s0 = qt * 128;
    int wq = wave * 32;
    int c = lane & 15, rr = lane >> 4;
    int cx = c & 7;                       // read-side XOR swizzle key

    const bf16* qbase  = qkvb + (size_t)b * SEQ * QKV_DIM + h * HD;
    const bf16* kbase  = qbase + D_MODEL;
    const bf16* vtbase = vt + (size_t)((b * N_HEADS + h) * HD) * SEQ;

    // stage Q [128 q][64 d] swizzled into Ps
    #pragma unroll
    for (int r = 0; r < 4; r++) {
        int lin = r * 256 + t;
        int qq = lin >> 3, p = lin & 7;
        int kc = p ^ (qq & 7);
        async_load16(qbase + (size_t)(s0 + qq) * QKV_DIM + kc * 8,
                     Ps + (size_t)(r * 256 + wave * 64) * 8);
    }
    // stage K/V tile 0 into buf 0
    #pragma unroll
    for (int r = 0; r < 2; r++) {
        int row = (r * 256 + t) >> 3;
        int kc = ((r * 256 + t) & 7) ^ (row & 7);
        async_load16(kbase + (size_t)row * QKV_DIM + kc * 8,
                     Ks + (size_t)(r * 256 + wave * 64) * 8);
        async_load16(vtbase + (size_t)row * SEQ + kc * 8,
                     Vts + (size_t)(r * 256 + wave * 64) * 8);
    }
    __syncthreads();   // drains Q + KV0

    bf16x8 bq[2][2];
    #pragma unroll
    for (int m = 0; m < 2; m++)
        #pragma unroll
        for (int kk = 0; kk < 2; kk++)
            bq[m][kk] = *(const bf16x8*)&Ps[(wq + m * 16 + c) * 64 + ((kk * 4 + rr) ^ cx) * 8];

    bf16x8 ones;
    #pragma unroll
    for (int i = 0; i < 8; i++) ones[i] = (short)0x3F80;   // bf16 1.0

    f32x4 Oa[2][4] = {};
    f32x4 La[2] = {};

    for (int jt = 0; jt < SEQ; jt += 64) {
        int cur = (jt >> 6) & 1;
        bf16* Kb  = Ks  + cur * 4096;
        bf16* Vtb = Vts + cur * 4096;

        if (jt + 64 < SEQ) {
            bf16* Kn  = Ks  + (cur ^ 1) * 4096;
            bf16* Vtn = Vts + (cur ^ 1) * 4096;
            #pragma unroll
            for (int r = 0; r < 2; r++) {
                int row = (r * 256 + t) >> 3;
                int kc = ((r * 256 + t) & 7) ^ (row & 7);
                async_load16(kbase + (size_t)(jt + 64 + row) * QKV_DIM + kc * 8,
                             Kn + (size_t)(r * 256 + wave * 64) * 8);
                async_load16(vtbase + (size_t)row * SEQ + (jt + 64) + kc * 8,
                             Vtn + (size_t)(r * 256 + wave * 64) * 8);
            }
        }

        // S^T = K Q^T : lane holds q = wq+m*16+c, j = jj*16 + rr*4 + [0..3]
        f32x4 St[4][2] = {};
        __builtin_amdgcn_s_setprio(1);
        #pragma unroll
        for (int kk = 0; kk < 2; kk++) {
            bf16x8 ak[4];
            #pragma unroll
            for (int jj = 0; jj < 4; jj++)
                ak[jj] = *(const bf16x8*)&Kb[(jj * 16 + c) * 64 + ((kk * 4 + rr) ^ cx) * 8];
            #pragma unroll
            for (int jj = 0; jj < 4; jj++)
                #pragma unroll
                for (int m = 0; m < 2; m++)
                    St[jj][m] = __builtin_amdgcn_mfma_f32_16x16x32_bf16(
                        ak[jj], bq[m][kk], St[jj][m], 0, 0, 0);
        }
        __builtin_amdgcn_s_setprio(0);

        // P = exp2(S'); fast-pack pairs -> one b64 store into swizzled Ps[q][j]
        #pragma unroll
        for (int jj = 0; jj < 4; jj++) {
            int off = ((jj * 2 + (rr >> 1)) ^ cx) * 8 + (rr & 1) * 4;
            #pragma unroll
            for (int m = 0; m < 2; m++) {
                float p0 = __builtin_amdgcn_exp2f(St[jj][m][0]);
                float p1 = __builtin_amdgcn_exp2f(St[jj][m][1]);
                float p2 = __builtin_amdgcn_exp2f(St[jj][m][2]);
                float p3 = __builtin_amdgcn_exp2f(St[jj][m][3]);
                uint2 pk;
                pk.x = pack_bf16_pair(p0, p1);
                pk.y = pack_bf16_pair(p2, p3);
                *(uint2*)&Ps[(wq + m * 16 + c) * 64 + off] = pk;
            }
        }

        // O += P V ; l += P · 1  (each wave reads only its own Ps rows)
        __builtin_amdgcn_s_setprio(1);
        #pragma unroll
        for (int kk = 0; kk < 2; kk++) {
            bf16x8 ap[2];
            #pragma unroll
            for (int m = 0; m < 2; m++)
                ap[m] = *(const bf16x8*)&Ps[(wq + m * 16 + c) * 64 + ((kk * 4 + rr) ^ cx) * 8];
            #pragma unroll
            for (int m = 0; m < 2; m++)
                La[m] = __builtin_amdgcn_mfma_f32_16x16x32_bf16(
                    ap[m], ones, La[m], 0, 0, 0);
            #pragma unroll
            for (int n = 0; n < 4; n++) {
                bf16x8 bv = *(const bf16x8*)&Vtb[(n * 16 + c) * 64 + ((kk * 4 + rr) ^ cx) * 8];
                #pragma unroll
                for (int m = 0; m < 2; m++)
                    Oa[m][n] = __builtin_amdgcn_mfma_f32_16x16x32_bf16(
                        ap[m], bv, Oa[m][n], 0, 0, 0);
            }
        }
        __builtin_amdgcn_s_setprio(0);

        __syncthreads();
    }

    // La[m][rg] is the row-sum for q-row rr*4+rg (same C-layout as Oa)
    #pragma unroll
    for (int m = 0; m < 2; m++)
        #pragma unroll
        for (int rg = 0; rg < 4; rg++) {
            float inv = __builtin_amdgcn_rcpf(La[m][rg]);
            int q = s0 + wq + m * 16 + rr * 4 + rg;
            bf16* op = o + (size_t)(b * SEQ + q) * D_MODEL + h * HD;
            #pragma unroll
            for (int n = 0; n < 4; n++)
                op[n * 16 + c] = __float2bfloat16(Oa[m][n][rg] * inv);
        }
}

extern "C" void kernel_launch(void* const* d_in, const int* in_sizes, int n_in,
                              void* d_out, int out_size, void* d_ws, size_t ws_size,
                              hipStream_t stream) {
    const float* x         = (const float*)d_in[0];
    const float* ln1_w     = (const float*)d_in[1];
    const float* ln1_b     = (const float*)d_in[2];
    const float* in_proj_w = (const float*)d_in[3];
    const float* in_proj_b = (const float*)d_in[4];
    const float* out_w     = (const float*)d_in[5];
    const float* out_b     = (const float*)d_in[6];
    const float* ln2_w     = (const float*)d_in[7];
    const float* ln2_b     = (const float*)d_in[8];
    const float* fc_w      = (const float*)d_in[9];
    const float* fc_b      = (const float*)d_in[10];
    const float* proj_w    = (const float*)d_in[11];
    const float* proj_b    = (const float*)d_in[12];

    float* out = (float*)d_out;
    char*  ws  = (char*)d_ws;

    bf16* qkvb = (bf16*)ws;                          // 37,748,736 B (dead after attn)
    bf16* vt   = (bf16*)(ws + 37748736);             // 12,582,912 B (dead after attn)
    bf16* ff   = (bf16*)ws;                          // reuses qkvb+vt
    bf16* h    = (bf16*)(ws + 50331648);             // 12,582,912 B
    bf16* o    = (bf16*)(ws + 62914560);             // 12,582,912 B
    bf16* wbf  = (bf16*)(ws + 75497472);             // 14,155,776 B
    bf16* wqkv_b  = wbf;
    bf16* wout_b  = wqkv_b + (size_t)QKV_DIM * D_MODEL;
    bf16* wfc_b   = wout_b + (size_t)D_MODEL * D_MODEL;
    bf16* wproj_b = wfc_b  + (size_t)D_FF * D_MODEL;

    int n0 = QKV_DIM * D_MODEL / 4, n1 = D_MODEL * D_MODEL / 4;
    int n2 = D_FF * D_MODEL / 4,    n3 = D_MODEL * D_FF / 4;
    int cast_blocks = (n0 + n1 + n2 + n3 + 255) / 256;

    // 1. h = LN1(x) fused with weight casts
    ln1_cast<<<M_ROWS + cast_blocks, 256, 0, stream>>>(
        x, ln1_w, ln1_b, h,
        in_proj_w, wqkv_b, n0, out_w, wout_b, n1, fc_w, wfc_b, n2, proj_w, wproj_b, n3);
    // 2. qkvb = h @ Wqkv^T + b  (Q cols scaled by 0.125*log2e) -- 256sq 8-phase
    gemm_256<3, bf16><<<dim3(QKV_DIM / 256, M_ROWS / 256), 512, 0, stream>>>(
        h, wqkv_b, in_proj_b, qkvb, M_ROWS, QKV_DIM, D_MODEL);
    // 3. vt = transpose of V part
    vtrans<<<dim3(SEQ / 64, N_HEADS, BATCH), 256, 0, stream>>>(qkvb, vt);
    // 4. o = attention(qkvb, vt)
    attn_mfma<<<dim3(SEQ / 128, N_HEADS, BATCH), 256, 0, stream>>>(qkvb, vt, o);
    // 5. out = x + o @ Wout^T + b
    gemm_mfma<2, float><<<dim3(D_MODEL / 128, M_ROWS / 128), 256, 0, stream>>>(
        o, wout_b, out_b, x, out, M_ROWS, D_MODEL, D_MODEL);
    // 6. h2 = LN2(out)
    ln_kernel<bf16><<<M_ROWS, 256, 0, stream>>>(out, ln2_w, ln2_b, h);
    // 7. ff = gelu(h2 @ Wfc^T + b) -- 256sq 8-phase
    gemm_256<1, bf16><<<dim3(D_FF / 256, M_ROWS / 256), 512, 0, stream>>>(
        h, wfc_b, fc_b, ff, M_ROWS, D_FF, D_MODEL);
    // 8. out += ff @ Wproj^T + b
    gemm_mfma<2, float><<<dim3(D_MODEL / 128, M_ROWS / 128), 256, 0, stream>>>(
        ff, wproj_b, proj_b, out, out, M_ROWS, D_MODEL, D_FF);
}

// Round 7
// 357.769 us; speedup vs baseline: 1.1025x; 1.1025x over previous
//
#include <hip/hip_runtime.h>
#include <hip/hip_bf16.h>
#include <math.h>

#define D_MODEL 768
#define N_HEADS 12
#define HD 64
#define SEQ 2048
#define BATCH 4
#define M_ROWS 8192
#define D_FF 3072
#define QKV_DIM 2304
#define LN_EPS 1e-5f
// 0.125 * log2(e): folded into Q so P = exp2(S') directly
#define Q_SCALE 0.18033688011112042f

typedef __attribute__((ext_vector_type(8))) short bf16x8;
typedef __attribute__((ext_vector_type(4))) float f32x4;
typedef __hip_bfloat16 bf16;

__device__ __forceinline__ void store_val(float* p, float v) { *p = v; }
__device__ __forceinline__ void store_val(bf16* p, float v) { *p = __float2bfloat16(v); }

// fast bf16 pair pack: round-half-up (add 0x8000) + v_perm high-half extract
__device__ __forceinline__ unsigned int pack_bf16_pair(float a, float b) {
    unsigned int ua = __builtin_bit_cast(unsigned int, a) + 0x8000u;
    unsigned int ub = __builtin_bit_cast(unsigned int, b) + 0x8000u;
    // D = {ub.hi16, ua.hi16}: sel bytes {7,6,3,2} of (s0=ub, s1=ua)
    return __builtin_amdgcn_perm(ub, ua, 0x07060302u);
}

__device__ __forceinline__ void async_load16(const void* g, void* l) {
    __builtin_amdgcn_global_load_lds(
        (const __attribute__((address_space(1))) void*)g,
        (__attribute__((address_space(3))) void*)l, 16, 0, 0);
}

// ---------------- LN1 (bf16 out) + fused weight casts -----------------
__global__ __launch_bounds__(256) void ln1_cast(
        const float* __restrict__ x, const float* __restrict__ w,
        const float* __restrict__ b, bf16* __restrict__ y,
        const float* __restrict__ s0, bf16* __restrict__ d0, int n0,
        const float* __restrict__ s1, bf16* __restrict__ d1, int n1,
        const float* __restrict__ s2, bf16* __restrict__ d2, int n2,
        const float* __restrict__ s3, bf16* __restrict__ d3, int n3) {
    int t = threadIdx.x;
    if (blockIdx.x >= M_ROWS) {
        int i = (blockIdx.x - M_ROWS) * 256 + t;   // float4 index
        const float* s; bf16* d; int local = i;
        if (local < n0) { s = s0; d = d0; }
        else {
            local -= n0;
            if (local < n1) { s = s1; d = d1; }
            else {
                local -= n1;
                if (local < n2) { s = s2; d = d2; }
                else {
                    local -= n2;
                    if (local >= n3) return;
                    s = s3; d = d3;
                }
            }
        }
        float4 v = ((const float4*)s)[local];
        uint2 pk;
        pk.x = pack_bf16_pair(v.x, v.y);
        pk.y = pack_bf16_pair(v.z, v.w);
        *(uint2*)(d + local * 4) = pk;
        return;
    }
    int row = blockIdx.x;
    const float* xr = x + (size_t)row * D_MODEL;
    bf16* yr = y + (size_t)row * D_MODEL;
    float v0 = xr[t], v1 = xr[t + 256], v2 = xr[t + 512];
    float s  = v0 + v1 + v2;
    float sq = v0 * v0 + v1 * v1 + v2 * v2;
    #pragma unroll
    for (int off = 32; off; off >>= 1) {
        s  += __shfl_xor(s, off);
        sq += __shfl_xor(sq, off);
    }
    __shared__ float ss[4], ssq[4];
    int wave = t >> 6;
    if ((t & 63) == 0) { ss[wave] = s; ssq[wave] = sq; }
    __syncthreads();
    s  = ss[0] + ss[1] + ss[2] + ss[3];
    sq = ssq[0] + ssq[1] + ssq[2] + ssq[3];
    float mean = s * (1.0f / D_MODEL);
    float var  = sq * (1.0f / D_MODEL) - mean * mean;
    float rstd = rsqrtf(var + LN_EPS);
    yr[t]       = __float2bfloat16((v0 - mean) * rstd * w[t]       + b[t]);
    yr[t + 256] = __float2bfloat16((v1 - mean) * rstd * w[t + 256] + b[t + 256]);
    yr[t + 512] = __float2bfloat16((v2 - mean) * rstd * w[t + 512] + b[t + 512]);
}

// ---------------- LayerNorm (LN2) ----------------
template <typename OutT>
__global__ __launch_bounds__(256) void ln_kernel(const float* __restrict__ x,
                                                 const float* __restrict__ w,
                                                 const float* __restrict__ b,
                                                 OutT* __restrict__ y) {
    int row = blockIdx.x;
    const float* xr = x + (size_t)row * D_MODEL;
    OutT* yr = y + (size_t)row * D_MODEL;
    int t = threadIdx.x;
    float v0 = xr[t], v1 = xr[t + 256], v2 = xr[t + 512];
    float s  = v0 + v1 + v2;
    float sq = v0 * v0 + v1 * v1 + v2 * v2;
    #pragma unroll
    for (int off = 32; off; off >>= 1) {
        s  += __shfl_xor(s, off);
        sq += __shfl_xor(sq, off);
    }
    __shared__ float ss[4], ssq[4];
    int wave = t >> 6;
    if ((t & 63) == 0) { ss[wave] = s; ssq[wave] = sq; }
    __syncthreads();
    s  = ss[0] + ss[1] + ss[2] + ss[3];
    sq = ssq[0] + ssq[1] + ssq[2] + ssq[3];
    float mean = s * (1.0f / D_MODEL);
    float var  = sq * (1.0f / D_MODEL) - mean * mean;
    float rstd = rsqrtf(var + LN_EPS);
    store_val(yr + t,       (v0 - mean) * rstd * w[t]       + b[t]);
    store_val(yr + t + 256, (v1 - mean) * rstd * w[t + 256] + b[t + 256]);
    store_val(yr + t + 512, (v2 - mean) * rstd * w[t + 512] + b[t + 512]);
}

// tanh-form GELU via hw exp2 + rcp (max abs err ~3e-4 vs erf form)
__device__ __forceinline__ float gelu_fast(float v) {
    float u = v * (0.7978845608f + 0.0356774081f * v * v);
    u = fminf(fmaxf(u, -10.0f), 10.0f);
    float e = __builtin_amdgcn_exp2f(u * 2.8853900818f);   // e = exp(2u)
    float th = (e - 1.0f) * __builtin_amdgcn_rcpf(e + 1.0f);
    return 0.5f * v * (1.0f + th);
}

// ---------------- bf16 MFMA GEMM v4: C = A[M,K] · W[N,K]^T + bias ----------
// Templated BM (64 or 128), BN=128, BK=64, 4 waves, 2 LDS buffers,
// counted vmcnt (no in-loop full drain), reg-staged fragments.
// BM=128: wave tile 64x64, 32 KB LDS, 2 blocks/CU (qkv, fc).
// BM=64:  wave tile 32x64, 48 KB LDS, 3 blocks/CU -- used for the N=768
//   GEMMs (out/proj): grid 6x128=768 blocks = exactly 3/CU, fixing the
//   25% idle-CU imbalance of 384-block 128-tiles (384 resident on 512
//   slots: half the CUs hold 1 block and finish early).
// K-loop per step: vmcnt(L) [stage(ki) landed, stage(ki+1) in flight] ->
// b1 -> ds_read all frags -> lgkmcnt(0) -> b2 -> issue STAGE(ki+2) into
// buf[cur] -> MFMA from regs. L = loads/thread = BM/32 + 4.
// FUSE: 0 = bias, 1 = bias+gelu, 2 = bias+resid(fp32), 3 = qkv (cols<768 *= Q_SCALE)
template <int FUSE, typename OutT, int BM = 128>
__global__ __launch_bounds__(256) void gemm_mfma(const bf16* __restrict__ A,
                                                 const bf16* __restrict__ W,
                                                 const float* __restrict__ bias,
                                                 const float* __restrict__ resid,
                                                 OutT* __restrict__ C,
                                                 int M, int N, int K) {
    const int BK = 64;
    const int LA = BM / 32;            // A loads per thread (2 or 4)
    const int MI = BM / 32;            // 16-row frags per wave tile (2 or 4)
    __shared__ __align__(16) bf16 As[2][BM * BK];
    __shared__ __align__(16) bf16 Bs[2][128 * BK];
    int t = threadIdx.x;
    int wave = t >> 6, lane = t & 63;

    // XCD-aware bijective remap of the flat block id (nwg % 8 == 0 always here)
    int nbx = gridDim.x;
    int w0 = blockIdx.x + nbx * blockIdx.y;
    int cpx = (nbx * gridDim.y) >> 3;
    int wg = (w0 & 7) * cpx + (w0 >> 3);
    int m_base = (wg / nbx) * BM, n_base = (wg % nbx) * 128;

    int wm = (wave >> 1) * (BM / 2), wn = (wave & 1) * 64;
    int c = lane & 15, rr = lane >> 4;
    int cx = c & 7;

    f32x4 acc[MI][4] = {};

    // staging: 16B-slot s = r*256 + t; row = s>>3, p = s&7;
    // fetch global chunk kc = p ^ (row&7)  (XOR swizzle via source mapping)
    const bf16* Ag[LA]; int loffA[LA];
    const bf16* Bg[4];  int loffB[4];
    #pragma unroll
    for (int r = 0; r < LA; r++) {
        int s = r * 256 + t;
        int row = s >> 3, p = s & 7;
        int kc = p ^ (row & 7);
        Ag[r] = A + (size_t)(m_base + row) * K + kc * 8;
        loffA[r] = (r * 256 + wave * 64) * 8;
    }
    #pragma unroll
    for (int r = 0; r < 4; r++) {
        int s = r * 256 + t;
        int row = s >> 3, p = s & 7;
        int kc = p ^ (row & 7);
        Bg[r] = W + (size_t)(n_base + row) * K + kc * 8;
        loffB[r] = (r * 256 + wave * 64) * 8;
    }

    auto STAGE = [&](int kt, int buf) {
        int k0 = kt * BK;
        #pragma unroll
        for (int r = 0; r < LA; r++)
            async_load16(Ag[r] + k0, As[buf] + loffA[r]);
        #pragma unroll
        for (int r = 0; r < 4; r++)
            async_load16(Bg[r] + k0, Bs[buf] + loffB[r]);
    };

    int nk = K / BK;
    STAGE(0, 0);
    STAGE(1, 1);

    for (int ki = 0; ki < nk; ki++) {
        int cur = ki & 1;
        if (ki < nk - 1) {
            // retire stage(ki); leave stage(ki+1)'s L loads in flight
            if (BM == 128) asm volatile("s_waitcnt vmcnt(8)" ::: "memory");
            else           asm volatile("s_waitcnt vmcnt(6)" ::: "memory");
        } else {
            asm volatile("s_waitcnt vmcnt(0)" ::: "memory");
        }
        __builtin_amdgcn_s_barrier();            // b1: buf[cur] ready
        __builtin_amdgcn_sched_barrier(0);

        // register-stage all fragments of tile ki (frees buf[cur])
        bf16x8 af[2][MI], bfr[2][4];
        #pragma unroll
        for (int kk = 0; kk < 2; kk++) {
            int sw = ((kk * 4 + rr) ^ cx) * 8;
            #pragma unroll
            for (int mi = 0; mi < MI; mi++)
                af[kk][mi] = *(const bf16x8*)&As[cur][(wm + mi * 16 + c) * BK + sw];
            #pragma unroll
            for (int ni = 0; ni < 4; ni++)
                bfr[kk][ni] = *(const bf16x8*)&Bs[cur][(wn + ni * 16 + c) * BK + sw];
        }
        asm volatile("s_waitcnt lgkmcnt(0)" ::: "memory");
        __builtin_amdgcn_s_barrier();            // b2: all waves read buf[cur]
        __builtin_amdgcn_sched_barrier(0);

        if (ki + 2 < nk) STAGE(ki + 2, cur);     // overwrite buf[cur]

        __builtin_amdgcn_s_setprio(1);
        #pragma unroll
        for (int kk = 0; kk < 2; kk++)
            #pragma unroll
            for (int mi = 0; mi < MI; mi++)
                #pragma unroll
                for (int ni = 0; ni < 4; ni++)
                    acc[mi][ni] = __builtin_amdgcn_mfma_f32_16x16x32_bf16(
                        bfr[kk][ni], af[kk][mi], acc[mi][ni], 0, 0, 0);
        __builtin_amdgcn_s_setprio(0);
    }

    // epilogue: acc[mi][ni][reg] = C[m_base+wm+mi*16+c][n_base+wn+ni*16+rr*4+reg]
    #pragma unroll
    for (int mi = 0; mi < MI; mi++) {
        int m = m_base + wm + mi * 16 + c;
        #pragma unroll
        for (int ni = 0; ni < 4; ni++) {
            int n0 = n_base + wn + ni * 16 + rr * 4;
            float4 bv = *(const float4*)&bias[n0];
            float v0 = acc[mi][ni][0] + bv.x;
            float v1 = acc[mi][ni][1] + bv.y;
            float v2 = acc[mi][ni][2] + bv.z;
            float v3 = acc[mi][ni][3] + bv.w;
            if (FUSE == 1) {
                v0 = gelu_fast(v0); v1 = gelu_fast(v1);
                v2 = gelu_fast(v2); v3 = gelu_fast(v3);
            }
            if (FUSE == 2) {
                float4 rv = *(const float4*)&resid[(size_t)m * N + n0];
                v0 += rv.x; v1 += rv.y; v2 += rv.z; v3 += rv.w;
            }
            if (FUSE == 3 && n0 < 768) {
                v0 *= Q_SCALE; v1 *= Q_SCALE; v2 *= Q_SCALE; v3 *= Q_SCALE;
            }
            OutT* dst = C + (size_t)m * N + n0;
            if (sizeof(OutT) == 4) {
                float4 st = {v0, v1, v2, v3};
                *(float4*)dst = st;
            } else {
                uint2 pk;
                pk.x = pack_bf16_pair(v0, v1);
                pk.y = pack_bf16_pair(v2, v3);
                *(uint2*)dst = pk;
            }
        }
    }
}

// ---------------- V transpose: qkvb V-part [s][d] -> vt[(b,h,d)][s] --------
__global__ __launch_bounds__(256) void vtrans(const bf16* __restrict__ qkvb,
                                              bf16* __restrict__ vt) {
    __shared__ bf16 T[64 * 72];
    int t = threadIdx.x;
    int s0 = blockIdx.x * 64, h = blockIdx.y, b = blockIdx.z;
    const bf16* src = qkvb + (size_t)(b * SEQ) * QKV_DIM + 2 * D_MODEL + h * HD;
    #pragma unroll
    for (int i = 0; i < 2; i++) {
        int idx = i * 256 + t;
        int sr = idx >> 3, ch = idx & 7;
        uint4 v = *(const uint4*)(src + (size_t)(s0 + sr) * QKV_DIM + ch * 8);
        *(uint4*)&T[sr * 72 + ch * 8] = v;
    }
    __syncthreads();
    int dr = t >> 2, part = t & 3;
    unsigned int w[8];
    #pragma unroll
    for (int i = 0; i < 8; i++) {
        unsigned short a, bsh;
        __builtin_memcpy(&a,   &T[(part * 16 + 2 * i    ) * 72 + dr], 2);
        __builtin_memcpy(&bsh, &T[(part * 16 + 2 * i + 1) * 72 + dr], 2);
        w[i] = (unsigned int)a | ((unsigned int)bsh << 16);
    }
    bf16* dst = vt + ((size_t)((b * N_HEADS + h) * HD + dr)) * SEQ + s0 + part * 16;
    uint4 p0; p0.x = w[0]; p0.y = w[1]; p0.z = w[2]; p0.w = w[3];
    uint4 p1; p1.x = w[4]; p1.y = w[5]; p1.z = w[6]; p1.w = w[7];
    *(uint4*)dst = p0;
    *(uint4*)(dst + 8) = p1;
}

// ---------------- MFMA flash attention ----------------
// Unchanged from round 5 (XCD swizzle cut HBM fetch 5.7x; kernel is
// softmax-VALU-bound at ~73 us -- structural plateau for this shape).
__global__ __launch_bounds__(256) void attn_mfma(const bf16* __restrict__ qkvb,
                                                 const bf16* __restrict__ vt,
                                                 bf16* __restrict__ o) {
    __shared__ __align__(16) bf16 Ks[2 * 64 * 64];    // 16 KB (dbuf)
    __shared__ __align__(16) bf16 Vts[2 * 64 * 64];   // 16 KB (dbuf)
    __shared__ __align__(16) bf16 Ps[128 * 64];       // 16 KB (also Q staging)

    int t = threadIdx.x;
    int wave = t >> 6, lane = t & 63;

    // XCD swizzle (bijective on 768): wg = (w%8)*96 + w/8
    int w0 = blockIdx.x + 16 * (blockIdx.y + 12 * blockIdx.z);
    int wg = (w0 & 7) * 96 + (w0 >> 3);
    int qt = wg & 15;
    int hb = wg >> 4;                 // 0..47
    int h = hb % 12, b = hb / 12;

    int s0 = qt * 128;
    int wq = wave * 32;
    int c = lane & 15, rr = lane >> 4;
    int cx = c & 7;                       // read-side XOR swizzle key

    const bf16* qbase  = qkvb + (size_t)b * SEQ * QKV_DIM + h * HD;
    const bf16* kbase  = qbase + D_MODEL;
    const bf16* vtbase = vt + (size_t)((b * N_HEADS + h) * HD) * SEQ;

    // stage Q [128 q][64 d] swizzled into Ps
    #pragma unroll
    for (int r = 0; r < 4; r++) {
        int lin = r * 256 + t;
        int qq = lin >> 3, p = lin & 7;
        int kc = p ^ (qq & 7);
        async_load16(qbase + (size_t)(s0 + qq) * QKV_DIM + kc * 8,
                     Ps + (size_t)(r * 256 + wave * 64) * 8);
    }
    // stage K/V tile 0 into buf 0
    #pragma unroll
    for (int r = 0; r < 2; r++) {
        int row = (r * 256 + t) >> 3;
        int kc = ((r * 256 + t) & 7) ^ (row & 7);
        async_load16(kbase + (size_t)row * QKV_DIM + kc * 8,
                     Ks + (size_t)(r * 256 + wave * 64) * 8);
        async_load16(vtbase + (size_t)row * SEQ + kc * 8,
                     Vts + (size_t)(r * 256 + wave * 64) * 8);
    }
    __syncthreads();   // drains Q + KV0

    bf16x8 bq[2][2];
    #pragma unroll
    for (int m = 0; m < 2; m++)
        #pragma unroll
        for (int kk = 0; kk < 2; kk++)
            bq[m][kk] = *(const bf16x8*)&Ps[(wq + m * 16 + c) * 64 + ((kk * 4 + rr) ^ cx) * 8];

    bf16x8 ones;
    #pragma unroll
    for (int i = 0; i < 8; i++) ones[i] = (short)0x3F80;   // bf16 1.0

    f32x4 Oa[2][4] = {};
    f32x4 La[2] = {};

    for (int jt = 0; jt < SEQ; jt += 64) {
        int cur = (jt >> 6) & 1;
        bf16* Kb  = Ks  + cur * 4096;
        bf16* Vtb = Vts + cur * 4096;

        if (jt + 64 < SEQ) {
            bf16* Kn  = Ks  + (cur ^ 1) * 4096;
            bf16* Vtn = Vts + (cur ^ 1) * 4096;
            #pragma unroll
            for (int r = 0; r < 2; r++) {
                int row = (r * 256 + t) >> 3;
                int kc = ((r * 256 + t) & 7) ^ (row & 7);
                async_load16(kbase + (size_t)(jt + 64 + row) * QKV_DIM + kc * 8,
                             Kn + (size_t)(r * 256 + wave * 64) * 8);
                async_load16(vtbase + (size_t)row * SEQ + (jt + 64) + kc * 8,
                             Vtn + (size_t)(r * 256 + wave * 64) * 8);
            }
        }

        // S^T = K Q^T : lane holds q = wq+m*16+c, j = jj*16 + rr*4 + [0..3]
        f32x4 St[4][2] = {};
        __builtin_amdgcn_s_setprio(1);
        #pragma unroll
        for (int kk = 0; kk < 2; kk++) {
            bf16x8 ak[4];
            #pragma unroll
            for (int jj = 0; jj < 4; jj++)
                ak[jj] = *(const bf16x8*)&Kb[(jj * 16 + c) * 64 + ((kk * 4 + rr) ^ cx) * 8];
            #pragma unroll
            for (int jj = 0; jj < 4; jj++)
                #pragma unroll
                for (int m = 0; m < 2; m++)
                    St[jj][m] = __builtin_amdgcn_mfma_f32_16x16x32_bf16(
                        ak[jj], bq[m][kk], St[jj][m], 0, 0, 0);
        }
        __builtin_amdgcn_s_setprio(0);

        // P = exp2(S'); fast-pack pairs -> one b64 store into swizzled Ps[q][j]
        #pragma unroll
        for (int jj = 0; jj < 4; jj++) {
            int off = ((jj * 2 + (rr >> 1)) ^ cx) * 8 + (rr & 1) * 4;
            #pragma unroll
            for (int m = 0; m < 2; m++) {
                float p0 = __builtin_amdgcn_exp2f(St[jj][m][0]);
                float p1 = __builtin_amdgcn_exp2f(St[jj][m][1]);
                float p2 = __builtin_amdgcn_exp2f(St[jj][m][2]);
                float p3 = __builtin_amdgcn_exp2f(St[jj][m][3]);
                uint2 pk;
                pk.x = pack_bf16_pair(p0, p1);
                pk.y = pack_bf16_pair(p2, p3);
                *(uint2*)&Ps[(wq + m * 16 + c) * 64 + off] = pk;
            }
        }

        // O += P V ; l += P · 1  (each wave reads only its own Ps rows)
        __builtin_amdgcn_s_setprio(1);
        #pragma unroll
        for (int kk = 0; kk < 2; kk++) {
            bf16x8 ap[2];
            #pragma unroll
            for (int m = 0; m < 2; m++)
                ap[m] = *(const bf16x8*)&Ps[(wq + m * 16 + c) * 64 + ((kk * 4 + rr) ^ cx) * 8];
            #pragma unroll
            for (int m = 0; m < 2; m++)
                La[m] = __builtin_amdgcn_mfma_f32_16x16x32_bf16(
                    ap[m], ones, La[m], 0, 0, 0);
            #pragma unroll
            for (int n = 0; n < 4; n++) {
                bf16x8 bv = *(const bf16x8*)&Vtb[(n * 16 + c) * 64 + ((kk * 4 + rr) ^ cx) * 8];
                #pragma unroll
                for (int m = 0; m < 2; m++)
                    Oa[m][n] = __builtin_amdgcn_mfma_f32_16x16x32_bf16(
                        ap[m], bv, Oa[m][n], 0, 0, 0);
            }
        }
        __builtin_amdgcn_s_setprio(0);

        __syncthreads();
    }

    // La[m][rg] is the row-sum for q-row rr*4+rg (same C-layout as Oa)
    #pragma unroll
    for (int m = 0; m < 2; m++)
        #pragma unroll
        for (int rg = 0; rg < 4; rg++) {
            float inv = __builtin_amdgcn_rcpf(La[m][rg]);
            int q = s0 + wq + m * 16 + rr * 4 + rg;
            bf16* op = o + (size_t)(b * SEQ + q) * D_MODEL + h * HD;
            #pragma unroll
            for (int n = 0; n < 4; n++)
                op[n * 16 + c] = __float2bfloat16(Oa[m][n][rg] * inv);
        }
}

extern "C" void kernel_launch(void* const* d_in, const int* in_sizes, int n_in,
                              void* d_out, int out_size, void* d_ws, size_t ws_size,
                              hipStream_t stream) {
    const float* x         = (const float*)d_in[0];
    const float* ln1_w     = (const float*)d_in[1];
    const float* ln1_b     = (const float*)d_in[2];
    const float* in_proj_w = (const float*)d_in[3];
    const float* in_proj_b = (const float*)d_in[4];
    const float* out_w     = (const float*)d_in[5];
    const float* out_b     = (const float*)d_in[6];
    const float* ln2_w     = (const float*)d_in[7];
    const float* ln2_b     = (const float*)d_in[8];
    const float* fc_w      = (const float*)d_in[9];
    const float* fc_b      = (const float*)d_in[10];
    const float* proj_w    = (const float*)d_in[11];
    const float* proj_b    = (const float*)d_in[12];

    float* out = (float*)d_out;
    char*  ws  = (char*)d_ws;

    bf16* qkvb = (bf16*)ws;                          // 37,748,736 B (dead after attn)
    bf16* vt   = (bf16*)(ws + 37748736);             // 12,582,912 B (dead after attn)
    bf16* ff   = (bf16*)ws;                          // reuses qkvb+vt
    bf16* h    = (bf16*)(ws + 50331648);             // 12,582,912 B
    bf16* o    = (bf16*)(ws + 62914560);             // 12,582,912 B
    bf16* wbf  = (bf16*)(ws + 75497472);             // 14,155,776 B
    bf16* wqkv_b  = wbf;
    bf16* wout_b  = wqkv_b + (size_t)QKV_DIM * D_MODEL;
    bf16* wfc_b   = wout_b + (size_t)D_MODEL * D_MODEL;
    bf16* wproj_b = wfc_b  + (size_t)D_FF * D_MODEL;

    int n0 = QKV_DIM * D_MODEL / 4, n1 = D_MODEL * D_MODEL / 4;
    int n2 = D_FF * D_MODEL / 4,    n3 = D_MODEL * D_FF / 4;
    int cast_blocks = (n0 + n1 + n2 + n3 + 255) / 256;

    // 1. h = LN1(x) fused with weight casts
    ln1_cast<<<M_ROWS + cast_blocks, 256, 0, stream>>>(
        x, ln1_w, ln1_b, h,
        in_proj_w, wqkv_b, n0, out_w, wout_b, n1, fc_w, wfc_b, n2, proj_w, wproj_b, n3);
    // 2. qkvb = h @ Wqkv^T + b  (Q cols scaled by 0.125*log2e)
    gemm_mfma<3, bf16, 128><<<dim3(QKV_DIM / 128, M_ROWS / 128), 256, 0, stream>>>(
        h, wqkv_b, in_proj_b, nullptr, qkvb, M_ROWS, QKV_DIM, D_MODEL);
    // 3. vt = transpose of V part
    vtrans<<<dim3(SEQ / 64, N_HEADS, BATCH), 256, 0, stream>>>(qkvb, vt);
    // 4. o = attention(qkvb, vt)
    attn_mfma<<<dim3(SEQ / 128, N_HEADS, BATCH), 256, 0, stream>>>(qkvb, vt, o);
    // 5. out = x + o @ Wout^T + b  (BM=64: 768 blocks = 3/CU, balanced)
    gemm_mfma<2, float, 64><<<dim3(D_MODEL / 128, M_ROWS / 64), 256, 0, stream>>>(
        o, wout_b, out_b, x, out, M_ROWS, D_MODEL, D_MODEL);
    // 6. h2 = LN2(out)
    ln_kernel<bf16><<<M_ROWS, 256, 0, stream>>>(out, ln2_w, ln2_b, h);
    // 7. ff = gelu(h2 @ Wfc^T + b)
    gemm_mfma<1, bf16, 128><<<dim3(D_FF / 128, M_ROWS / 128), 256, 0, stream>>>(
        h, wfc_b, fc_b, nullptr, ff, M_ROWS, D_FF, D_MODEL);
    // 8. out += ff @ Wproj^T + b  (BM=64: 768 blocks = 3/CU, balanced)
    gemm_mfma<2, float, 64><<<dim3(D_MODEL / 128, M_ROWS / 64), 256, 0, stream>>>(
        ff, wproj_b, proj_b, out, out, M_ROWS, D_MODEL, D_FF);
}